// Round 14
// baseline (4855.832 us; speedup 1.0000x reference)
//
#include <hip/hip_runtime.h>
#include <math.h>

// Problem constants (fixed by the reference)
constexpr int N_ = 101, H_ = 128;
constexpr float EPS_ = 1e-5f;

// Static LDS (float words) — 14,584 words = 58,336 B  (2 blocks/CU: 116.7 KB < 160 KB)
constexpr int OFF_TAB = 0;                    // 13,032: staging (stride 129) -> final QEF (stride 128)
constexpr int OFF_AT  = 13032;                // 816: attn weights (8 x 101); setup: pool partials
constexpr int OFF_XV  = OFF_AT + 816;         // 144: x (padded-36 chunks)
constexpr int OFF_YR  = OFF_XV + 144;         // 144: y raw (padded-36 chunks)
constexpr int OFF_CP  = OFF_YR + 144;         // 128: comp (setup: pool_proc)
constexpr int OFF_RS  = OFF_CP + 128;         // 320: efsum[104], efs2[104], effc[104], scalars@312
constexpr int LDS_WORDS = OFF_RS + 320;

__device__ __forceinline__ float rdlane(float v, int l) {
  return __int_as_float(__builtin_amdgcn_readlane(__float_as_int(v), l));
}
template<int CTRL, int RM>
__device__ __forceinline__ float dppadd(float x) {
  int v = __builtin_amdgcn_update_dpp(0, __float_as_int(x), CTRL, RM, 0xf, true);
  return x + __int_as_float(v);
}
template<int CTRL, int RM>
__device__ __forceinline__ float dppmax(float x) {
  int v = __builtin_amdgcn_update_dpp(__float_as_int(x), __float_as_int(x), CTRL, RM, 0xf, false);
  return fmaxf(x, __int_as_float(v));
}
__device__ __forceinline__ float wave_sum(float x) {
  x = dppadd<0x111,0xf>(x); x = dppadd<0x112,0xf>(x);
  x = dppadd<0x114,0xf>(x); x = dppadd<0x118,0xf>(x);
  x = dppadd<0x142,0xa>(x); x = dppadd<0x143,0xc>(x);
  return rdlane(x, 63);
}
__device__ __forceinline__ float wave_max(float x) {
  x = dppmax<0x111,0xf>(x); x = dppmax<0x112,0xf>(x);
  x = dppmax<0x114,0xf>(x); x = dppmax<0x118,0xf>(x);
  x = dppmax<0x142,0xa>(x); x = dppmax<0x143,0xc>(x);
  return rdlane(x, 63);
}
__device__ __forceinline__ float grp4_sum(float x) {   // valid at lane 4c+3
  x = dppadd<0x111,0xf>(x);
  x = dppadd<0x112,0xf>(x);
  return x;
}
__device__ __forceinline__ int swz(int k) { return (k >> 5) * 36 + (k & 31); }

__global__ __launch_bounds__(512, 4) void gat_decoder(
    const float* __restrict__ enc, const float* __restrict__ pool,
    const float* __restrict__ capac, const float* __restrict__ dem,
    const float* __restrict__ fcw, const float* __restrict__ fc1w,
    const float* __restrict__ lng, const float* __restrict__ lnb,
    const float* __restrict__ wq, const float* __restrict__ wk,
    const float* __restrict__ wvm, const float* __restrict__ wo,
    const float* __restrict__ kpw, const float* __restrict__ plg,
    const float* __restrict__ plb, const int* __restrict__ tp,
    float* __restrict__ out, int Bv, int ns)
{
  __shared__ float sm[LDS_WORDS];
  const int tid  = threadIdx.x;
  const int b    = blockIdx.x;
  const int lane = tid & 63;
  const int wvid = tid >> 6;        // wave id 0..7 (= head id)
  const int sl   = lane & 3;        // k-slice (adjacent lanes -> 2-hop DPP)
  const int lc   = lane >> 2;       // local column 0..15
  const int col  = wvid * 16 + lc;  // output column owned by this thread
  const int n1 = lane, n2 = lane + 64;

  const float NEG_INF = -__builtin_inff();
  int ti = tp[0];
  float Tf = (ti > 1000000 || ti < -1000000) ? __int_as_float((int)ti) : (float)ti;
  const float inv_sqrt_h = 1.0f / sqrtf(128.0f);
  const float PSUM_CONST = 1.0f + (float)N_ * 1e-10f;

  const float* encb = enc + (size_t)b * (N_ * H_);

  float* TAB = sm + OFF_TAB;   // staging (stride 129) then QEF (stride 128)
  float* AT = sm + OFF_AT;   float* XVp = sm + OFF_XV;
  float* YRp = sm + OFF_YR;  float* CP = sm + OFF_CP;
  float* RS = sm + OFF_RS;

  const int j3 = tid & 127;
  const int g3 = __builtin_amdgcn_readfirstlane(tid >> 7);
  const int r03 = g3 * 26, nr3 = (g3 == 3) ? 23 : 26;

  // ===== S0: pool partials -> AT ; Kp -> TAB =====
  {
    const float* pb = pool + (size_t)b * H_;
    float p = 0.f;
    #pragma unroll
    for (int r = 0; r < 32; ++r) p = fmaf(pb[g3 * 32 + r], fc1w[(g3 * 32 + r) * H_ + j3], p);
    AT[g3 * 128 + j3] = p;
  }
  {
    float acc[26];
    #pragma unroll
    for (int t = 0; t < 26; ++t) acc[t] = 0.f;
    for (int k0 = 0; k0 < H_; k0 += 8) {
      float w8[8];
      #pragma unroll
      for (int kk = 0; kk < 8; ++kk) w8[kk] = kpw[(k0 + kk) * H_ + j3];
      #pragma unroll
      for (int t = 0; t < 26; ++t) if (t < nr3) {
        const float* ep = encb + (r03 + t) * H_ + k0;
        #pragma unroll
        for (int kk = 0; kk < 8; ++kk) acc[t] = fmaf(ep[kk], w8[kk], acc[t]);
      }
    }
    #pragma unroll
    for (int t = 0; t < 26; ++t) if (t < nr3) TAB[(r03 + t) * 129 + j3] = acc[t];
  }
  __syncthreads();

  // ===== S1: pool_proc -> CP ; kpT extract + pointer-LN fold =====
  if (tid < 128) CP[tid] = AT[tid] + AT[128 + tid] + AT[256 + tid] + AT[384 + tid];
  float kpT[32], kps, cpb;
  {
    const int neff = (col < N_) ? col : (N_ - 1);
    const float* src = TAB + neff * 129 + sl * 32;
    float ks = 0.f, cb = 0.f;
    #pragma unroll
    for (int r = 0; r < 32; ++r) {
      const float kv = src[r];
      const float pg = plg[sl * 32 + r];
      const float pb2 = plb[sl * 32 + r];
      ks = fmaf(kv, pg, ks);
      cb = fmaf(kv, pb2, cb);
      kpT[r] = kv * pg;
    }
    kps = grp4_sum(ks); cpb = grp4_sum(cb);
  }
  __syncthreads();

  // ===== S2: K -> TAB =====
  {
    float acc[26];
    #pragma unroll
    for (int t = 0; t < 26; ++t) acc[t] = 0.f;
    for (int k0 = 0; k0 < H_; k0 += 8) {
      float w8[8];
      #pragma unroll
      for (int kk = 0; kk < 8; ++kk) w8[kk] = wk[(k0 + kk) * H_ + j3];
      #pragma unroll
      for (int t = 0; t < 26; ++t) if (t < nr3) {
        const float* ep = encb + (r03 + t) * H_ + k0;
        #pragma unroll
        for (int kk = 0; kk < 8; ++kk) acc[t] = fmaf(ep[kk], w8[kk], acc[t]);
      }
    }
    #pragma unroll
    for (int t = 0; t < 26; ++t) if (t < nr3) TAB[(r03 + t) * 129 + j3] = acc[t];
  }
  __syncthreads();

  // ===== S3: K head-slices -> registers (khA = K[n1], khB = K[n2]) =====
  float khA[16], khB[16];
  {
    const int row2 = (n2 < N_) ? n2 : n1;
    const float* s1 = TAB + n1 * 129 + wvid * 16;
    const float* s2 = TAB + row2 * 129 + wvid * 16;
    #pragma unroll
    for (int d = 0; d < 16; ++d) { khA[d] = s1[d]; khB[d] = s2[d]; }
  }
  __syncthreads();

  // ===== S4: EF' = enc@fc_w + pool_proc -> TAB =====
  {
    const float pcj = CP[j3];
    float acc[26];
    #pragma unroll
    for (int t = 0; t < 26; ++t) acc[t] = pcj;
    for (int k0 = 0; k0 < H_; k0 += 8) {
      float w8[8];
      #pragma unroll
      for (int kk = 0; kk < 8; ++kk) w8[kk] = fcw[(k0 + kk) * H_ + j3];
      #pragma unroll
      for (int t = 0; t < 26; ++t) if (t < nr3) {
        const float* ep = encb + (r03 + t) * H_ + k0;
        #pragma unroll
        for (int kk = 0; kk < 8; ++kk) acc[t] = fmaf(ep[kk], w8[kk], acc[t]);
      }
    }
    #pragma unroll
    for (int t = 0; t < 26; ++t) if (t < nr3) TAB[(r03 + t) * 129 + j3] = acc[t];
  }
  __syncthreads();

  // ===== S5: row stats -> RS ; qacc = EF'@wq' into registers =====
  if (tid < N_) {
    const float* base = TAB + tid * 129;
    float s = 0.f, s2 = 0.f, sf = 0.f, fs = 0.f, fs2 = 0.f;
    for (int r = 0; r < 128; ++r) {
      const float v = base[r];
      const float fr = fcw[128 * H_ + r];
      s += v; s2 = fmaf(v, v, s2); sf = fmaf(v, fr, sf);
      fs += fr; fs2 = fmaf(fr, fr, fs2);
    }
    RS[tid] = s; RS[104 + tid] = s2; RS[208 + tid] = sf;
    if (tid == 0) { RS[312] = fs; RS[313] = fs2; }
  }
  float qacc[26];
  {
    #pragma unroll
    for (int t = 0; t < 26; ++t) qacc[t] = 0.f;
    for (int k0 = 0; k0 < H_; k0 += 8) {
      float w8[8];
      #pragma unroll
      for (int kk = 0; kk < 8; ++kk) w8[kk] = wq[(k0 + kk) * H_ + j3] * lng[k0 + kk];
      #pragma unroll
      for (int t = 0; t < 26; ++t) if (t < nr3) {
        const float* erow = TAB + (r03 + t) * 129 + k0;   // LDS broadcast
        #pragma unroll
        for (int kk = 0; kk < 8; ++kk) qacc[t] = fmaf(erow[kk], w8[kk], qacc[t]);
      }
    }
  }
  __syncthreads();

  // ===== S6: QEF (stride 128) overwrites TAB ; reg tables ; state =====
  #pragma unroll
  for (int t = 0; t < 26; ++t) if (t < nr3) TAB[(r03 + t) * 128 + j3] = qacc[t];
  // V col-slices
  float vh[26];
  {
    const int r0v = sl * 26, nrv = (sl == 3) ? 23 : 26;
    #pragma unroll
    for (int t = 0; t < 26; ++t) vh[t] = 0.f;
    for (int k0 = 0; k0 < H_; k0 += 8) {
      float w8[8];
      #pragma unroll
      for (int kk = 0; kk < 8; ++kk) w8[kk] = wvm[(k0 + kk) * H_ + col];
      #pragma unroll
      for (int t = 0; t < 26; ++t) if (t < nrv) {
        const float* ep = encb + (r0v + t) * H_ + k0;
        #pragma unroll
        for (int kk = 0; kk < 8; ++kk) vh[t] = fmaf(ep[kk], w8[kk], vh[t]);
      }
    }
  }
  float wo_r[32];
  #pragma unroll
  for (int r = 0; r < 32; ++r) wo_r[r] = wo[(sl * 32 + r) * H_ + col];
  float wqs = 0.f, qb = 0.f, wfc = 0.f;
  for (int r = 0; r < 128; ++r) {
    const float w = wq[r * H_ + col];
    const float lg = lng[r], lb = lnb[r], fr = fcw[128 * H_ + r];
    wqs = fmaf(w, lg, wqs);
    qb  = fmaf(w, lb, qb);
    wfc = fmaf(w * lg, fr, wfc);
  }
  const float capv = capac[b];
  float cap = capv, lpsum = 0.f;
  float demA = dem[(size_t)b * N_ + n1];
  float demC = (n2 < N_) ? dem[(size_t)b * N_ + n2] : 0.f;
  int vis = 0, pidx = 0;
  bool m1a = false, m1c = false, mbA, mbB;
  {
    bool infA = (n1 >= 1) && (demA > cap);
    bool infB = (n2 >= N_) || (demC > cap);
    bool feasA = (n1 >= 1) && !infA;
    bool feasB = (n2 < N_) && !infB;
    const bool anyf = __any(feasA || feasB);
    mbA = (n1 == 0) ? anyf : infA;
    mbB = infB;
  }
  __syncthreads();
  const float fcsum = RS[312], fcs2 = RS[313];

  // ===== decode loop: 3 barriers/step =====
  for (int i = 0; i < ns; ++i) {
    const int pu = __builtin_amdgcn_readfirstlane(pidx);

    // Q: folded stats + folded q (QEF lookup); logits from reg K; softmax; X
    {
      const float efsum = RS[pu], efs2 = RS[104 + pu], effc = RS[208 + pu];
      const float mu = (efsum + cap * fcsum) * (1.f / 128.f);
      const float msq = (efs2 + 2.f * cap * effc + cap * cap * fcs2) * (1.f / 128.f);
      const float inv = 1.0f / sqrtf(msq - mu * mu + EPS_);
      const float qefv = TAB[pu * 128 + col];
      const float q = inv * (qefv + cap * wfc - mu * wqs) + qb;
      float a1 = 0.f, a2r = 0.f;
      #pragma unroll
      for (int d = 0; d < 16; ++d) {
        const float qdv = rdlane(q, 4 * d);
        a1  = fmaf(qdv, khA[d], a1);
        a2r = fmaf(qdv, khB[d], a2r);
      }
      a1 = mbA ? NEG_INF : a1 * 0.25f;
      float a2 = (n2 < N_ && !mbB) ? a2r * 0.25f : NEG_INF;
      const float mx = wave_max(fmaxf(a1, a2));
      float e1 = expf(a1 - mx);
      float e2 = (n2 < N_) ? expf(a2 - mx) : 0.f;
      const float ss = wave_sum(e1 + e2);
      AT[wvid * N_ + n1] = e1 / ss;
      if (n2 < N_) AT[wvid * N_ + n2] = e2 / ss;
      // X: x[col] = attn(head) @ V — same-wave AT reads
      const float* aw = AT + wvid * N_ + sl * 26;
      const int nrv = (sl == 3) ? 23 : 26;
      float x = 0.f;
      #pragma unroll
      for (int t = 0; t < 26; ++t) if (t < nrv) x = fmaf(aw[t], vh[t], x);
      x = grp4_sum(x);
      if (sl == 3) XVp[swz(col)] = x;
    }
    __syncthreads();                                            // bar1

    // Y: y[col] = x @ wo
    {
      const float4* xp4 = (const float4*)(XVp + sl * 36);
      float y = 0.f;
      #pragma unroll
      for (int r4 = 0; r4 < 8; ++r4) {
        const float4 u = xp4[r4];
        y = fmaf(wo_r[r4 * 4 + 0], u.x, y);
        y = fmaf(wo_r[r4 * 4 + 1], u.y, y);
        y = fmaf(wo_r[r4 * 4 + 2], u.z, y);
        y = fmaf(wo_r[r4 * 4 + 3], u.w, y);
      }
      y = grp4_sum(y);
      if (sl == 3) YRp[swz(col)] = y;
    }
    __syncthreads();                                            // bar2

    // C: LN stats (DPP) || folded comp matvec with kpT'
    {
      const float YA = YRp[swz(n1)], YC = YRp[swz(n2 & 127)];
      const float mu = wave_sum(YA + YC) * (1.f / 128.f);
      const float da = YA - mu, dc = YC - mu;
      const float inv = 1.0f / sqrtf(wave_sum(da * da + dc * dc) * (1.f / 128.f) + EPS_);
      const float4* yp4 = (const float4*)(YRp + sl * 36);
      float c = 0.f;
      #pragma unroll
      for (int r4 = 0; r4 < 8; ++r4) {
        const float4 u = yp4[r4];
        c = fmaf(kpT[r4 * 4 + 0], u.x, c);
        c = fmaf(kpT[r4 * 4 + 1], u.y, c);
        c = fmaf(kpT[r4 * 4 + 2], u.z, c);
        c = fmaf(kpT[r4 * 4 + 3], u.w, c);
      }
      c = grp4_sum(c);
      const float comp = inv * (c - mu * kps) + cpb;
      if (sl == 3 && col < N_) CP[col] = comp;
    }
    __syncthreads();                                            // bar3

    // AM — all waves redundantly
    {
      const bool allmb = __all(mbA && mbB);
      float c1 = mbA ? NEG_INF : CP[n1] * inv_sqrt_h / Tf;
      float c2 = (n2 < N_ && !mbB) ? CP[n2 & 127] * inv_sqrt_h / Tf : NEG_INF;
      if (allmb) { c1 = 0.f; c2 = (n2 < N_) ? 0.f : NEG_INF; }
      const float mx = wave_max(fmaxf(c1, c2));
      const unsigned long long b1 = __ballot(c1 == mx);
      const unsigned long long b2 = __ballot(c2 == mx);
      const int bis = b1 ? (__ffsll((long long)b1) - 1)
                         : (64 + __ffsll((long long)b2) - 1);
      float e1 = expf(c1 - mx);
      float e2 = (n2 < N_) ? expf(c2 - mx) : 0.f;
      const float ss = wave_sum(e1 + e2);
      float lp = logf((1.0f / ss + 1e-10f) / PSUM_CONST);
      if (vis >= N_ - 1) lp = 0.f;
      lpsum += lp;
      const float dsel = (bis < 64) ? rdlane(demA, bis) : rdlane(demC, bis - 64);
      cap = (bis == 0) ? capv : (cap - dsel);
      if (bis != 0) {
        const bool newly = ((bis == n1) && !m1a) || ((bis == n2) && !m1c);
        if (__any(newly)) vis += 1;
        m1a = m1a || (bis == n1);
        m1c = m1c || (bis == n2);
      }
      bool infA = (n1 >= 1) && (m1a || demA > cap);
      bool infB = (n2 >= N_) || m1c || (demC > cap);
      bool feasA = (n1 >= 1) && !infA;
      bool feasB = (n2 < N_) && !infB;
      const bool anyf = __any(feasA || feasB);
      const bool depot_m = anyf && (bis == 0);
      mbA = (n1 == 0) ? depot_m : infA;
      mbB = infB;
      pidx = bis;
      if (wvid == 0 && lane == 0) out[(size_t)b * (ns + 2) + 1 + i] = (float)bis;
    }
    // hazards: next Q writes AT (same-wave) and XVp (last read in Y, >=2 barriers back). safe.
  }

  if (wvid == 0 && lane == 0) {
    out[(size_t)b * (ns + 2)] = 0.f;
    out[(size_t)b * (ns + 2) + ns + 1] = (pidx == 0) ? -1.f : 0.f;
    out[(size_t)Bv * (ns + 2) + b] = lpsum;   // log_p
  }
}

extern "C" void kernel_launch(void* const* d_in, const int* in_sizes, int n_in,
                              void* d_out, int out_size, void* d_ws, size_t ws_size,
                              hipStream_t stream) {
  const int Bv = in_sizes[0] / (N_ * H_);   // 1024
  const int ns = out_size / Bv - 3;         // 120
  gat_decoder<<<dim3(Bv), dim3(512), 0, stream>>>(
      (const float*)d_in[0],  (const float*)d_in[1],  (const float*)d_in[2],
      (const float*)d_in[3],  (const float*)d_in[4],  (const float*)d_in[5],
      (const float*)d_in[6],  (const float*)d_in[7],  (const float*)d_in[8],
      (const float*)d_in[9],  (const float*)d_in[10], (const float*)d_in[11],
      (const float*)d_in[12], (const float*)d_in[13], (const float*)d_in[14],
      (const int*)d_in[16],
      (float*)d_out, Bv, ns);
}

// Round 15
// 4799.872 us; speedup vs baseline: 1.0117x; 1.0117x over previous
//
#include <hip/hip_runtime.h>
#include <math.h>

constexpr int N_ = 101, H_ = 128;
constexpr float EPS_ = 1e-5f;

// Dynamic LDS layout (float words) — 29,216 words = 116,864 B
constexpr int OFF_REGA = 0;        // 13,056: staging (129-stride) -> QEF_A (128-stride)
constexpr int OFF_REGB = 13056;    // 13,056: same for batch B
constexpr int OFF_ATA  = 26112;    // 816
constexpr int OFF_ATB  = 26928;    // 816
constexpr int OFF_XVA  = 27744;    // 144 (padded-36 chunks)
constexpr int OFF_XVB  = 27888;    // 144
constexpr int OFF_YRA  = 28032;    // 144
constexpr int OFF_YRB  = 28176;    // 144
constexpr int OFF_CPA  = 28320;    // 128 (setup: pool_proc A)
constexpr int OFF_CPB  = 28448;    // 128
constexpr int OFF_RSA  = 28576;    // 320
constexpr int OFF_RSB  = 28896;    // 320
constexpr int LDS_WORDS = 29216;
constexpr int LDS_BYTES = LDS_WORDS * 4;

__device__ __forceinline__ float rdlane(float v, int l) {
  return __int_as_float(__builtin_amdgcn_readlane(__float_as_int(v), l));
}
template<int CTRL, int RM>
__device__ __forceinline__ float dppadd(float x) {
  int v = __builtin_amdgcn_update_dpp(0, __float_as_int(x), CTRL, RM, 0xf, true);
  return x + __int_as_float(v);
}
template<int CTRL, int RM>
__device__ __forceinline__ float dppmax(float x) {
  int v = __builtin_amdgcn_update_dpp(__float_as_int(x), __float_as_int(x), CTRL, RM, 0xf, false);
  return fmaxf(x, __int_as_float(v));
}
__device__ __forceinline__ float wave_sum(float x) {
  x = dppadd<0x111,0xf>(x); x = dppadd<0x112,0xf>(x);
  x = dppadd<0x114,0xf>(x); x = dppadd<0x118,0xf>(x);
  x = dppadd<0x142,0xa>(x); x = dppadd<0x143,0xc>(x);
  return rdlane(x, 63);
}
__device__ __forceinline__ float wave_max(float x) {
  x = dppmax<0x111,0xf>(x); x = dppmax<0x112,0xf>(x);
  x = dppmax<0x114,0xf>(x); x = dppmax<0x118,0xf>(x);
  x = dppmax<0x142,0xa>(x); x = dppmax<0x143,0xc>(x);
  return rdlane(x, 63);
}
__device__ __forceinline__ float grp4_sum(float x) {   // valid at lane 4c+3
  x = dppadd<0x111,0xf>(x);
  x = dppadd<0x112,0xf>(x);
  return x;
}
__device__ __forceinline__ int swz(int k) { return (k >> 5) * 36 + (k & 31); }

// enc@W (+init) -> REG at stride 129 (26 rows per 128-thread group)
__device__ __forceinline__ void stage_tab(const float* __restrict__ W,
                                          const float* __restrict__ ENCB,
                                          float* __restrict__ REG,
                                          int j3, int r03, int nr3, float init)
{
  float acc[26];
  #pragma unroll
  for (int t = 0; t < 26; ++t) acc[t] = init;
  for (int k0 = 0; k0 < H_; k0 += 8) {
    float w8[8];
    #pragma unroll
    for (int kk = 0; kk < 8; ++kk) w8[kk] = W[(k0 + kk) * H_ + j3];
    #pragma unroll
    for (int t = 0; t < 26; ++t) if (t < nr3) {
      const float* ep = ENCB + (r03 + t) * H_ + k0;
      #pragma unroll
      for (int kk = 0; kk < 8; ++kk) acc[t] = fmaf(ep[kk], w8[kk], acc[t]);
    }
  }
  #pragma unroll
  for (int t = 0; t < 26; ++t) if (t < nr3) REG[(r03 + t) * 129 + j3] = acc[t];
}

__device__ __forceinline__ void row_stats(const float* __restrict__ REG,
                                          float* __restrict__ RS,
                                          const float* __restrict__ fcw, int tid)
{
  if (tid < N_) {
    const float* base = REG + tid * 129;
    float s = 0.f, s2 = 0.f, sf = 0.f, fs = 0.f, fs2 = 0.f;
    for (int r = 0; r < 128; ++r) {
      const float v = base[r];
      const float fr = fcw[128 * H_ + r];
      s += v; s2 = fmaf(v, v, s2); sf = fmaf(v, fr, sf);
      fs += fr; fs2 = fmaf(fr, fr, fs2);
    }
    RS[tid] = s; RS[104 + tid] = s2; RS[208 + tid] = sf;
    if (tid == 0) { RS[312] = fs; RS[313] = fs2; }
  }
}

__device__ __forceinline__ void qef_compute(const float* __restrict__ REG,
                                            const float* __restrict__ wq,
                                            const float* __restrict__ lng,
                                            int j3, int r03, int nr3, float (&qacc)[26])
{
  #pragma unroll
  for (int t = 0; t < 26; ++t) qacc[t] = 0.f;
  for (int k0 = 0; k0 < H_; k0 += 8) {
    float w8[8];
    #pragma unroll
    for (int kk = 0; kk < 8; ++kk) w8[kk] = wq[(k0 + kk) * H_ + j3] * lng[k0 + kk];
    #pragma unroll
    for (int t = 0; t < 26; ++t) if (t < nr3) {
      const float* erow = REG + (r03 + t) * 129 + k0;
      #pragma unroll
      for (int kk = 0; kk < 8; ++kk) qacc[t] = fmaf(erow[kk], w8[kk], qacc[t]);
    }
  }
}

__global__ __launch_bounds__(512, 1) void gat_decoder(
    const float* __restrict__ enc, const float* __restrict__ pool,
    const float* __restrict__ capac, const float* __restrict__ dem,
    const float* __restrict__ fcw, const float* __restrict__ fc1w,
    const float* __restrict__ lng, const float* __restrict__ lnb,
    const float* __restrict__ wq, const float* __restrict__ wk,
    const float* __restrict__ wvm, const float* __restrict__ wo,
    const float* __restrict__ kpw, const float* __restrict__ plg,
    const float* __restrict__ plb, const int* __restrict__ tp,
    float* __restrict__ out, int Bv, int ns)
{
  extern __shared__ float sm[];
  const int tid  = threadIdx.x;
  const int lane = tid & 63;
  const int wvid = tid >> 6;        // wave id 0..7 (= head id)
  const int sl   = lane & 3;        // k-slice (adjacent lanes -> 2-hop DPP)
  const int lc   = lane >> 2;       // local column 0..15
  const int col  = wvid * 16 + lc;  // output column owned by this thread
  const int n1 = lane, n2 = lane + 64;
  const int b0 = blockIdx.x * 2, b1 = b0 + 1;

  const float NEG_INF = -__builtin_inff();
  int ti = tp[0];
  float Tf = (ti > 1000000 || ti < -1000000) ? __int_as_float((int)ti) : (float)ti;
  const float inv_sqrt_h = 1.0f / sqrtf(128.0f);
  const float sT = inv_sqrt_h / Tf;           // exact when T==1
  const float PSUM_CONST = 1.0f + (float)N_ * 1e-10f;

  const float* encA = enc + (size_t)b0 * (N_ * H_);
  const float* encB = enc + (size_t)b1 * (N_ * H_);

  float* REG_A = sm + OFF_REGA; float* REG_B = sm + OFF_REGB;
  float* AT_A = sm + OFF_ATA;   float* AT_B = sm + OFF_ATB;
  float* XV_A = sm + OFF_XVA;   float* XV_B = sm + OFF_XVB;
  float* YR_A = sm + OFF_YRA;   float* YR_B = sm + OFF_YRB;
  float* CP_A = sm + OFF_CPA;   float* CP_B = sm + OFF_CPB;
  float* RS_A = sm + OFF_RSA;   float* RS_B = sm + OFF_RSB;

  const int j3 = tid & 127;
  const int g3 = __builtin_amdgcn_readfirstlane(tid >> 7);
  const int r03 = g3 * 26, nr3 = (g3 == 3) ? 23 : 26;

  // ===== S0: pool partials for both batches =====
  {
    const float* pa = pool + (size_t)b0 * H_;
    const float* pb = pool + (size_t)b1 * H_;
    float sa = 0.f, sb = 0.f;
    #pragma unroll
    for (int r = 0; r < 32; ++r) {
      const float w = fc1w[(g3 * 32 + r) * H_ + j3];
      sa = fmaf(pa[g3 * 32 + r], w, sa);
      sb = fmaf(pb[g3 * 32 + r], w, sb);
    }
    AT_A[g3 * 128 + j3] = sa;
    AT_B[g3 * 128 + j3] = sb;
  }
  __syncthreads();
  if (tid < 128) {
    CP_A[tid] = AT_A[tid] + AT_A[128 + tid] + AT_A[256 + tid] + AT_A[384 + tid];
    CP_B[tid] = AT_B[tid] + AT_B[128 + tid] + AT_B[256 + tid] + AT_B[384 + tid];
  }

  // ===== S1: Kp staging =====
  stage_tab(kpw, encA, REG_A, j3, r03, nr3, 0.f);
  stage_tab(kpw, encB, REG_B, j3, r03, nr3, 0.f);
  __syncthreads();
  // kpT extract + pointer-LN fold (per batch)
  float kpT_a[32], kps_a, cpb_a, kpT_b[32], kps_b, cpb_b;
  {
    const int neff = (col < N_) ? col : (N_ - 1);
    const float* sa = REG_A + neff * 129 + sl * 32;
    const float* sb = REG_B + neff * 129 + sl * 32;
    float ka = 0.f, ca = 0.f, kb = 0.f, cb = 0.f;
    #pragma unroll
    for (int r = 0; r < 32; ++r) {
      const float pg = plg[sl * 32 + r];
      const float pl = plb[sl * 32 + r];
      const float va = sa[r], vb = sb[r];
      ka = fmaf(va, pg, ka); ca = fmaf(va, pl, ca);
      kb = fmaf(vb, pg, kb); cb = fmaf(vb, pl, cb);
      kpT_a[r] = va * pg; kpT_b[r] = vb * pg;
    }
    kps_a = grp4_sum(ka); cpb_a = grp4_sum(ca);
    kps_b = grp4_sum(kb); cpb_b = grp4_sum(cb);
  }
  __syncthreads();

  // ===== S2: K staging =====
  stage_tab(wk, encA, REG_A, j3, r03, nr3, 0.f);
  stage_tab(wk, encB, REG_B, j3, r03, nr3, 0.f);
  __syncthreads();
  float khA_a[16], khB_a[16], khA_b[16], khB_b[16];
  {
    const int row2 = (n2 < N_) ? n2 : n1;
    const float* a1p = REG_A + n1 * 129 + wvid * 16;
    const float* a2p = REG_A + row2 * 129 + wvid * 16;
    const float* b1p = REG_B + n1 * 129 + wvid * 16;
    const float* b2p = REG_B + row2 * 129 + wvid * 16;
    #pragma unroll
    for (int d = 0; d < 16; ++d) {
      khA_a[d] = a1p[d]; khB_a[d] = a2p[d];
      khA_b[d] = b1p[d]; khB_b[d] = b2p[d];
    }
  }
  __syncthreads();

  // ===== S3: EF' staging (enc@fc_w + pool_proc) =====
  stage_tab(fcw, encA, REG_A, j3, r03, nr3, CP_A[j3]);
  stage_tab(fcw, encB, REG_B, j3, r03, nr3, CP_B[j3]);
  __syncthreads();

  // ===== S4: stats + QEF (A then B to bound temp liveness) =====
  row_stats(REG_A, RS_A, fcw, tid);
  {
    float qacc[26];
    qef_compute(REG_A, wq, lng, j3, r03, nr3, qacc);
    __syncthreads();
    #pragma unroll
    for (int t = 0; t < 26; ++t) if (t < nr3) REG_A[(r03 + t) * 128 + j3] = qacc[t];
  }
  row_stats(REG_B, RS_B, fcw, tid);
  {
    float qacc[26];
    qef_compute(REG_B, wq, lng, j3, r03, nr3, qacc);
    __syncthreads();
    #pragma unroll
    for (int t = 0; t < 26; ++t) if (t < nr3) REG_B[(r03 + t) * 128 + j3] = qacc[t];
  }

  // ===== S5: V col-slices per batch =====
  float vh_a[26], vh_b[26];
  {
    const int r0v = sl * 26, nrv = (sl == 3) ? 23 : 26;
    #pragma unroll
    for (int t = 0; t < 26; ++t) { vh_a[t] = 0.f; vh_b[t] = 0.f; }
    for (int k0 = 0; k0 < H_; k0 += 8) {
      float w8[8];
      #pragma unroll
      for (int kk = 0; kk < 8; ++kk) w8[kk] = wvm[(k0 + kk) * H_ + col];
      #pragma unroll
      for (int t = 0; t < 26; ++t) if (t < nrv) {
        const float* ea = encA + (r0v + t) * H_ + k0;
        const float* eb = encB + (r0v + t) * H_ + k0;
        #pragma unroll
        for (int kk = 0; kk < 8; ++kk) {
          vh_a[t] = fmaf(ea[kk], w8[kk], vh_a[t]);
          vh_b[t] = fmaf(eb[kk], w8[kk], vh_b[t]);
        }
      }
    }
  }
  // wo rows (shared) + folded col scalars (shared)
  float wo_r[32];
  #pragma unroll
  for (int r = 0; r < 32; ++r) wo_r[r] = wo[(sl * 32 + r) * H_ + col];
  float wqs = 0.f, qb = 0.f, wfc = 0.f;
  for (int r = 0; r < 128; ++r) {
    const float w = wq[r * H_ + col];
    const float lg = lng[r], lb = lnb[r], fr = fcw[128 * H_ + r];
    wqs = fmaf(w, lg, wqs);
    qb  = fmaf(w, lb, qb);
    wfc = fmaf(w * lg, fr, wfc);
  }
  // per-batch decode state (redundant in every wave)
  const float capv_a = capac[b0], capv_b = capac[b1];
  float cap_a = capv_a, cap_b = capv_b, lpsum_a = 0.f, lpsum_b = 0.f;
  float demA_a = dem[(size_t)b0 * N_ + n1];
  float demC_a = (n2 < N_) ? dem[(size_t)b0 * N_ + n2] : 0.f;
  float demA_b = dem[(size_t)b1 * N_ + n1];
  float demC_b = (n2 < N_) ? dem[(size_t)b1 * N_ + n2] : 0.f;
  int vis_a = 0, pidx_a = 0, vis_b = 0, pidx_b = 0;
  bool m1a_a = false, m1c_a = false, mbA_a, mbB_a;
  bool m1a_b = false, m1c_b = false, mbA_b, mbB_b;
  {
    bool infA = (n1 >= 1) && (demA_a > cap_a);
    bool infB = (n2 >= N_) || (demC_a > cap_a);
    const bool anyf = __any(((n1 >= 1) && !infA) || ((n2 < N_) && !infB));
    mbA_a = (n1 == 0) ? anyf : infA;
    mbB_a = infB;
  }
  {
    bool infA = (n1 >= 1) && (demA_b > cap_b);
    bool infB = (n2 >= N_) || (demC_b > cap_b);
    const bool anyf = __any(((n1 >= 1) && !infA) || ((n2 < N_) && !infB));
    mbA_b = (n1 == 0) ? anyf : infA;
    mbB_b = infB;
  }
  __syncthreads();
  const float fcsum = RS_A[312], fcs2 = RS_A[313];

  // ===== decode loop: 3 barriers/step, both batches per phase =====
  for (int i = 0; i < ns; ++i) {
    // ---- Q phase (A then B; independent chains interleave) ----
    {
      const int pu = __builtin_amdgcn_readfirstlane(pidx_a);
      const float efsum = RS_A[pu], efs2 = RS_A[104 + pu], effc = RS_A[208 + pu];
      const float mu = (efsum + cap_a * fcsum) * (1.f / 128.f);
      const float msq = (efs2 + 2.f * cap_a * effc + cap_a * cap_a * fcs2) * (1.f / 128.f);
      const float inv = 1.0f / sqrtf(msq - mu * mu + EPS_);
      const float q = inv * (REG_A[pu * 128 + col] + cap_a * wfc - mu * wqs) + qb;
      float a1 = 0.f, a2r = 0.f;
      #pragma unroll
      for (int d = 0; d < 16; ++d) {
        const float qdv = rdlane(q, 4 * d);
        a1  = fmaf(qdv, khA_a[d], a1);
        a2r = fmaf(qdv, khB_a[d], a2r);
      }
      a1 = mbA_a ? NEG_INF : a1 * 0.25f;
      float a2 = (n2 < N_ && !mbB_a) ? a2r * 0.25f : NEG_INF;
      const float mx = wave_max(fmaxf(a1, a2));
      float e1 = expf(a1 - mx);
      float e2 = (n2 < N_) ? expf(a2 - mx) : 0.f;
      const float ss = wave_sum(e1 + e2);
      AT_A[wvid * N_ + n1] = e1 / ss;
      if (n2 < N_) AT_A[wvid * N_ + n2] = e2 / ss;
      const float* aw = AT_A + wvid * N_ + sl * 26;
      const int nrv = (sl == 3) ? 23 : 26;
      float x = 0.f;
      #pragma unroll
      for (int t = 0; t < 26; ++t) if (t < nrv) x = fmaf(aw[t], vh_a[t], x);
      x = grp4_sum(x);
      if (sl == 3) XV_A[swz(col)] = x;
    }
    {
      const int pu = __builtin_amdgcn_readfirstlane(pidx_b);
      const float efsum = RS_B[pu], efs2 = RS_B[104 + pu], effc = RS_B[208 + pu];
      const float mu = (efsum + cap_b * fcsum) * (1.f / 128.f);
      const float msq = (efs2 + 2.f * cap_b * effc + cap_b * cap_b * fcs2) * (1.f / 128.f);
      const float inv = 1.0f / sqrtf(msq - mu * mu + EPS_);
      const float q = inv * (REG_B[pu * 128 + col] + cap_b * wfc - mu * wqs) + qb;
      float a1 = 0.f, a2r = 0.f;
      #pragma unroll
      for (int d = 0; d < 16; ++d) {
        const float qdv = rdlane(q, 4 * d);
        a1  = fmaf(qdv, khA_b[d], a1);
        a2r = fmaf(qdv, khB_b[d], a2r);
      }
      a1 = mbA_b ? NEG_INF : a1 * 0.25f;
      float a2 = (n2 < N_ && !mbB_b) ? a2r * 0.25f : NEG_INF;
      const float mx = wave_max(fmaxf(a1, a2));
      float e1 = expf(a1 - mx);
      float e2 = (n2 < N_) ? expf(a2 - mx) : 0.f;
      const float ss = wave_sum(e1 + e2);
      AT_B[wvid * N_ + n1] = e1 / ss;
      if (n2 < N_) AT_B[wvid * N_ + n2] = e2 / ss;
      const float* aw = AT_B + wvid * N_ + sl * 26;
      const int nrv = (sl == 3) ? 23 : 26;
      float x = 0.f;
      #pragma unroll
      for (int t = 0; t < 26; ++t) if (t < nrv) x = fmaf(aw[t], vh_b[t], x);
      x = grp4_sum(x);
      if (sl == 3) XV_B[swz(col)] = x;
    }
    __syncthreads();                                            // bar1

    // ---- Y phase ----
    {
      const float4* xa = (const float4*)(XV_A + sl * 36);
      const float4* xb = (const float4*)(XV_B + sl * 36);
      float ya = 0.f, yb = 0.f;
      #pragma unroll
      for (int r4 = 0; r4 < 8; ++r4) {
        const float4 ua = xa[r4], ub = xb[r4];
        ya = fmaf(wo_r[r4*4+0], ua.x, ya); yb = fmaf(wo_r[r4*4+0], ub.x, yb);
        ya = fmaf(wo_r[r4*4+1], ua.y, ya); yb = fmaf(wo_r[r4*4+1], ub.y, yb);
        ya = fmaf(wo_r[r4*4+2], ua.z, ya); yb = fmaf(wo_r[r4*4+2], ub.z, yb);
        ya = fmaf(wo_r[r4*4+3], ua.w, ya); yb = fmaf(wo_r[r4*4+3], ub.w, yb);
      }
      ya = grp4_sum(ya); yb = grp4_sum(yb);
      if (sl == 3) { YR_A[swz(col)] = ya; YR_B[swz(col)] = yb; }
    }
    __syncthreads();                                            // bar2

    // ---- C phase ----
    {
      const float YA = YR_A[swz(n1)], YC = YR_A[swz(n2 & 127)];
      const float mu = wave_sum(YA + YC) * (1.f / 128.f);
      const float da = YA - mu, dc = YC - mu;
      const float inv = 1.0f / sqrtf(wave_sum(da * da + dc * dc) * (1.f / 128.f) + EPS_);
      const float4* yp4 = (const float4*)(YR_A + sl * 36);
      float c = 0.f;
      #pragma unroll
      for (int r4 = 0; r4 < 8; ++r4) {
        const float4 u = yp4[r4];
        c = fmaf(kpT_a[r4*4+0], u.x, c);
        c = fmaf(kpT_a[r4*4+1], u.y, c);
        c = fmaf(kpT_a[r4*4+2], u.z, c);
        c = fmaf(kpT_a[r4*4+3], u.w, c);
      }
      c = grp4_sum(c);
      const float comp = inv * (c - mu * kps_a) + cpb_a;
      if (sl == 3 && col < N_) CP_A[col] = comp;
    }
    {
      const float YA = YR_B[swz(n1)], YC = YR_B[swz(n2 & 127)];
      const float mu = wave_sum(YA + YC) * (1.f / 128.f);
      const float da = YA - mu, dc = YC - mu;
      const float inv = 1.0f / sqrtf(wave_sum(da * da + dc * dc) * (1.f / 128.f) + EPS_);
      const float4* yp4 = (const float4*)(YR_B + sl * 36);
      float c = 0.f;
      #pragma unroll
      for (int r4 = 0; r4 < 8; ++r4) {
        const float4 u = yp4[r4];
        c = fmaf(kpT_b[r4*4+0], u.x, c);
        c = fmaf(kpT_b[r4*4+1], u.y, c);
        c = fmaf(kpT_b[r4*4+2], u.z, c);
        c = fmaf(kpT_b[r4*4+3], u.w, c);
      }
      c = grp4_sum(c);
      const float comp = inv * (c - mu * kps_b) + cpb_b;
      if (sl == 3 && col < N_) CP_B[col] = comp;
    }
    __syncthreads();                                            // bar3

    // ---- AM phase (all waves redundantly, per batch) ----
    {
      const bool allmb = __all(mbA_a && mbB_a);
      float c1 = mbA_a ? NEG_INF : CP_A[n1] * sT;
      float c2 = (n2 < N_ && !mbB_a) ? CP_A[n2 & 127] * sT : NEG_INF;
      if (allmb) { c1 = 0.f; c2 = (n2 < N_) ? 0.f : NEG_INF; }
      const float mx = wave_max(fmaxf(c1, c2));
      const unsigned long long q1 = __ballot(c1 == mx);
      const unsigned long long q2 = __ballot(c2 == mx);
      const int bis = q1 ? (__ffsll((long long)q1) - 1) : (64 + __ffsll((long long)q2) - 1);
      float e1 = expf(c1 - mx);
      float e2 = (n2 < N_) ? expf(c2 - mx) : 0.f;
      const float ss = wave_sum(e1 + e2);
      float lp = logf((1.0f / ss + 1e-10f) / PSUM_CONST);
      if (vis_a >= N_ - 1) lp = 0.f;
      lpsum_a += lp;
      const float dsel = (bis < 64) ? rdlane(demA_a, bis) : rdlane(demC_a, bis - 64);
      cap_a = (bis == 0) ? capv_a : (cap_a - dsel);
      if (bis != 0) {
        const bool newly = ((bis == n1) && !m1a_a) || ((bis == n2) && !m1c_a);
        if (__any(newly)) vis_a += 1;
        m1a_a = m1a_a || (bis == n1);
        m1c_a = m1c_a || (bis == n2);
      }
      bool infA = (n1 >= 1) && (m1a_a || demA_a > cap_a);
      bool infB = (n2 >= N_) || m1c_a || (demC_a > cap_a);
      const bool anyf = __any(((n1 >= 1) && !infA) || ((n2 < N_) && !infB));
      mbA_a = (n1 == 0) ? (anyf && (bis == 0)) : infA;
      mbB_a = infB;
      pidx_a = bis;
      if (wvid == 0 && lane == 0) out[(size_t)b0 * (ns + 2) + 1 + i] = (float)bis;
    }
    {
      const bool allmb = __all(mbA_b && mbB_b);
      float c1 = mbA_b ? NEG_INF : CP_B[n1] * sT;
      float c2 = (n2 < N_ && !mbB_b) ? CP_B[n2 & 127] * sT : NEG_INF;
      if (allmb) { c1 = 0.f; c2 = (n2 < N_) ? 0.f : NEG_INF; }
      const float mx = wave_max(fmaxf(c1, c2));
      const unsigned long long q1 = __ballot(c1 == mx);
      const unsigned long long q2 = __ballot(c2 == mx);
      const int bis = q1 ? (__ffsll((long long)q1) - 1) : (64 + __ffsll((long long)q2) - 1);
      float e1 = expf(c1 - mx);
      float e2 = (n2 < N_) ? expf(c2 - mx) : 0.f;
      const float ss = wave_sum(e1 + e2);
      float lp = logf((1.0f / ss + 1e-10f) / PSUM_CONST);
      if (vis_b >= N_ - 1) lp = 0.f;
      lpsum_b += lp;
      const float dsel = (bis < 64) ? rdlane(demA_b, bis) : rdlane(demC_b, bis - 64);
      cap_b = (bis == 0) ? capv_b : (cap_b - dsel);
      if (bis != 0) {
        const bool newly = ((bis == n1) && !m1a_b) || ((bis == n2) && !m1c_b);
        if (__any(newly)) vis_b += 1;
        m1a_b = m1a_b || (bis == n1);
        m1c_b = m1c_b || (bis == n2);
      }
      bool infA = (n1 >= 1) && (m1a_b || demA_b > cap_b);
      bool infB = (n2 >= N_) || m1c_b || (demC_b > cap_b);
      const bool anyf = __any(((n1 >= 1) && !infA) || ((n2 < N_) && !infB));
      mbA_b = (n1 == 0) ? (anyf && (bis == 0)) : infA;
      mbB_b = infB;
      pidx_b = bis;
      if (wvid == 0 && lane == 0) out[(size_t)b1 * (ns + 2) + 1 + i] = (float)bis;
    }
    // hazards: AT same-wave; XV/YR/CP next writes are >=2 barriers past last readers. safe.
  }

  if (wvid == 0 && lane == 0) {
    out[(size_t)b0 * (ns + 2)] = 0.f;
    out[(size_t)b0 * (ns + 2) + ns + 1] = (pidx_a == 0) ? -1.f : 0.f;
    out[(size_t)Bv * (ns + 2) + b0] = lpsum_a;
    out[(size_t)b1 * (ns + 2)] = 0.f;
    out[(size_t)b1 * (ns + 2) + ns + 1] = (pidx_b == 0) ? -1.f : 0.f;
    out[(size_t)Bv * (ns + 2) + b1] = lpsum_b;
  }
}

extern "C" void kernel_launch(void* const* d_in, const int* in_sizes, int n_in,
                              void* d_out, int out_size, void* d_ws, size_t ws_size,
                              hipStream_t stream) {
  const int Bv = in_sizes[0] / (N_ * H_);   // 1024
  const int ns = out_size / Bv - 3;         // 120
  (void)hipFuncSetAttribute(reinterpret_cast<const void*>(gat_decoder),
                            hipFuncAttributeMaxDynamicSharedMemorySize, LDS_BYTES);
  gat_decoder<<<dim3(Bv / 2), dim3(512), LDS_BYTES, stream>>>(
      (const float*)d_in[0],  (const float*)d_in[1],  (const float*)d_in[2],
      (const float*)d_in[3],  (const float*)d_in[4],  (const float*)d_in[5],
      (const float*)d_in[6],  (const float*)d_in[7],  (const float*)d_in[8],
      (const float*)d_in[9],  (const float*)d_in[10], (const float*)d_in[11],
      (const float*)d_in[12], (const float*)d_in[13], (const float*)d_in[14],
      (const int*)d_in[16],
      (float*)d_out, Bv, ns);
}

// Round 16
// 2920.385 us; speedup vs baseline: 1.6627x; 1.6436x over previous
//
#include <hip/hip_runtime.h>
#include <math.h>

// Problem constants (fixed by the reference)
constexpr int N_ = 101, H_ = 128;
constexpr float EPS_ = 1e-5f;

// Dynamic LDS layout (float words) — 27,512 words = 110,048 B
constexpr int OFF_QEF = 0;                    // 101x128: QEF = EF'@wq'
constexpr int OFF_KT  = 12928;                // 101x129 (13032): staging Kp/EF', then K
constexpr int OFF_AT  = 25960;                // 816: attn weights (8 x 101); setup: pool partials
constexpr int OFF_XV  = 26776;                // 144: x (padded-36 chunks)
constexpr int OFF_YR  = 26920;                // 144: y raw (padded-36 chunks)
constexpr int OFF_CP  = 27064;                // 128: comp (setup: pool_proc)
constexpr int OFF_RS  = 27192;                // 320: efsum[104], efs2[104], effc[104], scalars@312
constexpr int LDS_WORDS = 27512;
constexpr int LDS_BYTES = LDS_WORDS * 4;

__device__ __forceinline__ float rdlane(float v, int l) {
  return __int_as_float(__builtin_amdgcn_readlane(__float_as_int(v), l));
}
// DPP reductions (verified r12)
template<int CTRL, int RM>
__device__ __forceinline__ float dppadd(float x) {
  int v = __builtin_amdgcn_update_dpp(0, __float_as_int(x), CTRL, RM, 0xf, true);
  return x + __int_as_float(v);
}
template<int CTRL, int RM>
__device__ __forceinline__ float dppmax(float x) {
  int v = __builtin_amdgcn_update_dpp(__float_as_int(x), __float_as_int(x), CTRL, RM, 0xf, false);
  return fmaxf(x, __int_as_float(v));
}
__device__ __forceinline__ float wave_sum(float x) {
  x = dppadd<0x111,0xf>(x); x = dppadd<0x112,0xf>(x);
  x = dppadd<0x114,0xf>(x); x = dppadd<0x118,0xf>(x);
  x = dppadd<0x142,0xa>(x); x = dppadd<0x143,0xc>(x);
  return rdlane(x, 63);
}
__device__ __forceinline__ float wave_max(float x) {
  x = dppmax<0x111,0xf>(x); x = dppmax<0x112,0xf>(x);
  x = dppmax<0x114,0xf>(x); x = dppmax<0x118,0xf>(x);
  x = dppmax<0x142,0xa>(x); x = dppmax<0x143,0xc>(x);
  return rdlane(x, 63);
}
__device__ __forceinline__ float grp4_sum(float x) {   // valid at lane 4c+3
  x = dppadd<0x111,0xf>(x);
  x = dppadd<0x112,0xf>(x);
  return x;
}
__device__ __forceinline__ int swz(int k) { return (k >> 5) * 36 + (k & 31); }

__global__ __launch_bounds__(512, 2) void gat_decoder(
    const float* __restrict__ enc, const float* __restrict__ pool,
    const float* __restrict__ capac, const float* __restrict__ dem,
    const float* __restrict__ fcw, const float* __restrict__ fc1w,
    const float* __restrict__ lng, const float* __restrict__ lnb,
    const float* __restrict__ wq, const float* __restrict__ wk,
    const float* __restrict__ wvm, const float* __restrict__ wo,
    const float* __restrict__ kpw, const float* __restrict__ plg,
    const float* __restrict__ plb, const int* __restrict__ tp,
    float* __restrict__ out, int Bv, int ns)
{
  extern __shared__ float sm[];
  const int tid  = threadIdx.x;
  const int b    = blockIdx.x;
  const int lane = tid & 63;
  const int wvid = tid >> 6;        // wave id 0..7 (= head id)
  const int sl   = lane & 3;        // k-slice (adjacent lanes -> 2-hop DPP)
  const int lc   = lane >> 2;       // local column 0..15
  const int col  = wvid * 16 + lc;  // output column owned by this thread
  const int n1 = lane, n2 = lane + 64;

  const float NEG_INF = -__builtin_inff();
  int ti = tp[0];
  float Tf = (ti > 1000000 || ti < -1000000) ? __int_as_float((int)ti) : (float)ti;
  const float inv_sqrt_h = 1.0f / sqrtf(128.0f);
  const float PSUM_CONST = 1.0f + (float)N_ * 1e-10f;

  const float* encb = enc + (size_t)b * (N_ * H_);

  float* QEF = sm + OFF_QEF; float* KT = sm + OFF_KT;
  float* AT = sm + OFF_AT;   float* XVp = sm + OFF_XV;
  float* YRp = sm + OFF_YR;  float* CP = sm + OFF_CP;
  float* RS = sm + OFF_RS;

  const int j3 = tid & 127;
  const int g3 = __builtin_amdgcn_readfirstlane(tid >> 7);
  const int r03 = g3 * 26, nr3 = (g3 == 3) ? 23 : 26;

  // ===== P0: pool partials -> AT ; Kp -> KT =====
  {
    const float* pb = pool + (size_t)b * H_;
    float p = 0.f;
    #pragma unroll
    for (int r = 0; r < 32; ++r) p = fmaf(pb[g3 * 32 + r], fc1w[(g3 * 32 + r) * H_ + j3], p);
    AT[g3 * 128 + j3] = p;
  }
  {
    float acc[26];
    #pragma unroll
    for (int t = 0; t < 26; ++t) acc[t] = 0.f;
    for (int k0 = 0; k0 < H_; k0 += 8) {
      float w8[8];
      #pragma unroll
      for (int kk = 0; kk < 8; ++kk) w8[kk] = kpw[(k0 + kk) * H_ + j3];
      #pragma unroll
      for (int t = 0; t < 26; ++t) if (t < nr3) {
        const float* ep = encb + (r03 + t) * H_ + k0;
        #pragma unroll
        for (int kk = 0; kk < 8; ++kk) acc[t] = fmaf(ep[kk], w8[kk], acc[t]);
      }
    }
    #pragma unroll
    for (int t = 0; t < 26; ++t) if (t < nr3) KT[(r03 + t) * 129 + j3] = acc[t];
  }
  __syncthreads();

  // ===== P1: pool_proc -> CP ; kpT extract + pointer-LN fold =====
  if (tid < 128) CP[tid] = AT[tid] + AT[128 + tid] + AT[256 + tid] + AT[384 + tid];
  float kpT[32], kps, cpb;
  {
    const int neff = (col < N_) ? col : (N_ - 1);
    const float* src = KT + neff * 129 + sl * 32;
    float ks = 0.f, cb = 0.f;
    #pragma unroll
    for (int r = 0; r < 32; ++r) {
      const float kv = src[r];
      const float pg = plg[sl * 32 + r];
      const float pb2 = plb[sl * 32 + r];
      ks = fmaf(kv, pg, ks);
      cb = fmaf(kv, pb2, cb);
      kpT[r] = kv * pg;
    }
    kps = grp4_sum(ks); cpb = grp4_sum(cb);
  }
  __syncthreads();

  // ===== P2: EF' = enc@fc_w + pool_proc -> KT =====
  {
    const float pcj = CP[j3];
    float acc[26];
    #pragma unroll
    for (int t = 0; t < 26; ++t) acc[t] = pcj;
    for (int k0 = 0; k0 < H_; k0 += 8) {
      float w8[8];
      #pragma unroll
      for (int kk = 0; kk < 8; ++kk) w8[kk] = fcw[(k0 + kk) * H_ + j3];
      #pragma unroll
      for (int t = 0; t < 26; ++t) if (t < nr3) {
        const float* ep = encb + (r03 + t) * H_ + k0;
        #pragma unroll
        for (int kk = 0; kk < 8; ++kk) acc[t] = fmaf(ep[kk], w8[kk], acc[t]);
      }
    }
    #pragma unroll
    for (int t = 0; t < 26; ++t) if (t < nr3) KT[(r03 + t) * 129 + j3] = acc[t];
  }
  __syncthreads();

  // ===== P3: QEF = EF'@wq' ; row stats -> RS =====
  {
    float qacc[26];
    #pragma unroll
    for (int t = 0; t < 26; ++t) qacc[t] = 0.f;
    for (int k0 = 0; k0 < H_; k0 += 8) {
      float w8[8];
      #pragma unroll
      for (int kk = 0; kk < 8; ++kk) w8[kk] = wq[(k0 + kk) * H_ + j3] * lng[k0 + kk];
      #pragma unroll
      for (int t = 0; t < 26; ++t) if (t < nr3) {
        const float* erow = KT + (r03 + t) * 129 + k0;   // LDS broadcast
        #pragma unroll
        for (int kk = 0; kk < 8; ++kk) qacc[t] = fmaf(erow[kk], w8[kk], qacc[t]);
      }
    }
    #pragma unroll
    for (int t = 0; t < 26; ++t) if (t < nr3) QEF[(r03 + t) * 128 + j3] = qacc[t];
  }
  if (tid < N_) {
    const float* base = KT + tid * 129;
    float s = 0.f, s2 = 0.f, sf = 0.f, fs = 0.f, fs2 = 0.f;
    for (int r = 0; r < 128; ++r) {
      const float v = base[r];
      const float fr = fcw[128 * H_ + r];
      s += v; s2 = fmaf(v, v, s2); sf = fmaf(v, fr, sf);
      fs += fr; fs2 = fmaf(fr, fr, fs2);
    }
    RS[tid] = s; RS[104 + tid] = s2; RS[208 + tid] = sf;
    if (tid == 0) { RS[312] = fs; RS[313] = fs2; }
  }
  __syncthreads();

  // ===== P4: K -> KT (overwrite EF') ; per-thread reg tables =====
  {
    float acc[26];
    #pragma unroll
    for (int t = 0; t < 26; ++t) acc[t] = 0.f;
    for (int k0 = 0; k0 < H_; k0 += 8) {
      float w8[8];
      #pragma unroll
      for (int kk = 0; kk < 8; ++kk) w8[kk] = wk[(k0 + kk) * H_ + j3];
      #pragma unroll
      for (int t = 0; t < 26; ++t) if (t < nr3) {
        const float* ep = encb + (r03 + t) * H_ + k0;
        #pragma unroll
        for (int kk = 0; kk < 8; ++kk) acc[t] = fmaf(ep[kk], w8[kk], acc[t]);
      }
    }
    #pragma unroll
    for (int t = 0; t < 26; ++t) if (t < nr3) KT[(r03 + t) * 129 + j3] = acc[t];
  }
  // V col-slices: vh[t] = V[sl*26+t][col]
  float vh[26];
  {
    const int r0v = sl * 26, nrv = (sl == 3) ? 23 : 26;
    #pragma unroll
    for (int t = 0; t < 26; ++t) vh[t] = 0.f;
    for (int k0 = 0; k0 < H_; k0 += 8) {
      float w8[8];
      #pragma unroll
      for (int kk = 0; kk < 8; ++kk) w8[kk] = wvm[(k0 + kk) * H_ + col];
      #pragma unroll
      for (int t = 0; t < 26; ++t) if (t < nrv) {
        const float* ep = encb + (r0v + t) * H_ + k0;
        #pragma unroll
        for (int kk = 0; kk < 8; ++kk) vh[t] = fmaf(ep[kk], w8[kk], vh[t]);
      }
    }
  }
  // wo rows for this thread's (sl, col)
  float wo_r[32];
  #pragma unroll
  for (int r = 0; r < 32; ++r) wo_r[r] = wo[(sl * 32 + r) * H_ + col];
  // per-col folded scalars: wqs, qb, wfc
  float wqs = 0.f, qb = 0.f, wfc = 0.f;
  for (int r = 0; r < 128; ++r) {
    const float w = wq[r * H_ + col];
    const float lg = lng[r], lb = lnb[r], fr = fcw[128 * H_ + r];
    wqs = fmaf(w, lg, wqs);
    qb  = fmaf(w, lb, qb);
    wfc = fmaf(w * lg, fr, wfc);
  }
  // per-wave redundant decode state
  const float capv = capac[b];
  float cap = capv, lpsum = 0.f;
  float demA = dem[(size_t)b * N_ + n1];
  float demC = (n2 < N_) ? dem[(size_t)b * N_ + n2] : 0.f;
  int vis = 0, pidx = 0;
  bool m1a = false, m1c = false, mbA, mbB;
  {
    bool infA = (n1 >= 1) && (demA > cap);
    bool infB = (n2 >= N_) || (demC > cap);
    bool feasA = (n1 >= 1) && !infA;
    bool feasB = (n2 < N_) && !infB;
    const bool anyf = __any(feasA || feasB);
    mbA = (n1 == 0) ? anyf : infA;
    mbB = infB;
  }
  __syncthreads();   // all tables ready
  const float fcsum = RS[312], fcs2 = RS[313];

  // ===== decode loop: 3 barriers/step, no global loads =====
  for (int i = 0; i < ns; ++i) {
    const int pu = __builtin_amdgcn_readfirstlane(pidx);

    // Q: folded stats + folded q; logits from LDS K; softmax; X
    {
      const float efsum = RS[pu], efs2 = RS[104 + pu], effc = RS[208 + pu];
      const float mu = (efsum + cap * fcsum) * (1.f / 128.f);
      const float msq = (efs2 + 2.f * cap * effc + cap * cap * fcs2) * (1.f / 128.f);
      const float inv = 1.0f / sqrtf(msq - mu * mu + EPS_);
      const float qefv = QEF[pu * 128 + col];
      const float q = inv * (qefv + cap * wfc - mu * wqs) + qb;
      // logits: q of head cols via readlane (quad-lane 4d holds col d of this wave's head)
      const float* kb1 = KT + n1 * 129 + wvid * 16;
      const float* kb2 = KT + ((n2 < N_) ? n2 : n1) * 129 + wvid * 16;
      float a1 = 0.f, a2r = 0.f;
      #pragma unroll
      for (int d = 0; d < 16; ++d) {
        const float qdv = rdlane(q, 4 * d);
        a1  = fmaf(qdv, kb1[d], a1);
        a2r = fmaf(qdv, kb2[d], a2r);
      }
      a1 = mbA ? NEG_INF : a1 * 0.25f;
      float a2 = (n2 < N_ && !mbB) ? a2r * 0.25f : NEG_INF;
      const float mx = wave_max(fmaxf(a1, a2));
      float e1 = expf(a1 - mx);
      float e2 = (n2 < N_) ? expf(a2 - mx) : 0.f;
      const float ss = wave_sum(e1 + e2);
      AT[wvid * N_ + n1] = e1 / ss;
      if (n2 < N_) AT[wvid * N_ + n2] = e2 / ss;
      // X: x[col] = attn(head) @ V — same-wave AT reads
      const float* aw = AT + wvid * N_ + sl * 26;
      const int nrv = (sl == 3) ? 23 : 26;
      float x = 0.f;
      #pragma unroll
      for (int t = 0; t < 26; ++t) if (t < nrv) x = fmaf(aw[t], vh[t], x);
      x = grp4_sum(x);
      if (sl == 3) XVp[swz(col)] = x;
    }
    __syncthreads();                                            // bar1

    // Y: y[col] = x @ wo  (padded-36 chunks -> conflict-free b128)
    {
      const float4* xp4 = (const float4*)(XVp + sl * 36);
      float y = 0.f;
      #pragma unroll
      for (int r4 = 0; r4 < 8; ++r4) {
        const float4 u = xp4[r4];
        y = fmaf(wo_r[r4 * 4 + 0], u.x, y);
        y = fmaf(wo_r[r4 * 4 + 1], u.y, y);
        y = fmaf(wo_r[r4 * 4 + 2], u.z, y);
        y = fmaf(wo_r[r4 * 4 + 3], u.w, y);
      }
      y = grp4_sum(y);
      if (sl == 3) YRp[swz(col)] = y;
    }
    __syncthreads();                                            // bar2

    // C: LN stats (DPP) || folded comp matvec with kpT'
    {
      const float YA = YRp[swz(n1)], YC = YRp[swz(n2 & 127)];
      const float mu = wave_sum(YA + YC) * (1.f / 128.f);
      const float da = YA - mu, dc = YC - mu;
      const float inv = 1.0f / sqrtf(wave_sum(da * da + dc * dc) * (1.f / 128.f) + EPS_);
      const float4* yp4 = (const float4*)(YRp + sl * 36);
      float c = 0.f;
      #pragma unroll
      for (int r4 = 0; r4 < 8; ++r4) {
        const float4 u = yp4[r4];
        c = fmaf(kpT[r4 * 4 + 0], u.x, c);
        c = fmaf(kpT[r4 * 4 + 1], u.y, c);
        c = fmaf(kpT[r4 * 4 + 2], u.z, c);
        c = fmaf(kpT[r4 * 4 + 3], u.w, c);
      }
      c = grp4_sum(c);
      const float comp = inv * (c - mu * kps) + cpb;
      if (sl == 3 && col < N_) CP[col] = comp;
    }
    __syncthreads();                                            // bar3

    // AM — all waves redundantly
    {
      const bool allmb = __all(mbA && mbB);
      float c1 = mbA ? NEG_INF : CP[n1] * inv_sqrt_h / Tf;
      float c2 = (n2 < N_ && !mbB) ? CP[n2 & 127] * inv_sqrt_h / Tf : NEG_INF;
      if (allmb) { c1 = 0.f; c2 = (n2 < N_) ? 0.f : NEG_INF; }
      const float mx = wave_max(fmaxf(c1, c2));
      const unsigned long long b1 = __ballot(c1 == mx);
      const unsigned long long b2 = __ballot(c2 == mx);
      const int bis = b1 ? (__ffsll((long long)b1) - 1)
                         : (64 + __ffsll((long long)b2) - 1);
      float e1 = expf(c1 - mx);
      float e2 = (n2 < N_) ? expf(c2 - mx) : 0.f;
      const float ss = wave_sum(e1 + e2);
      float lp = logf((1.0f / ss + 1e-10f) / PSUM_CONST);
      if (vis >= N_ - 1) lp = 0.f;
      lpsum += lp;
      const float dsel = (bis < 64) ? rdlane(demA, bis) : rdlane(demC, bis - 64);
      cap = (bis == 0) ? capv : (cap - dsel);
      if (bis != 0) {
        const bool newly = ((bis == n1) && !m1a) || ((bis == n2) && !m1c);
        if (__any(newly)) vis += 1;
        m1a = m1a || (bis == n1);
        m1c = m1c || (bis == n2);
      }
      bool infA = (n1 >= 1) && (m1a || demA > cap);
      bool infB = (n2 >= N_) || m1c || (demC > cap);
      bool feasA = (n1 >= 1) && !infA;
      bool feasB = (n2 < N_) && !infB;
      const bool anyf = __any(feasA || feasB);
      const bool depot_m = anyf && (bis == 0);
      mbA = (n1 == 0) ? depot_m : infA;
      mbB = infB;
      pidx = bis;
      if (wvid == 0 && lane == 0) out[(size_t)b * (ns + 2) + 1 + i] = (float)bis;
    }
    // hazards: next Q writes AT (same-wave) and XVp (last read in Y, 2 barriers back). safe.
  }

  if (wvid == 0 && lane == 0) {
    out[(size_t)b * (ns + 2)] = 0.f;
    out[(size_t)b * (ns + 2) + ns + 1] = (pidx == 0) ? -1.f : 0.f;
    out[(size_t)Bv * (ns + 2) + b] = lpsum;   // log_p
  }
}

extern "C" void kernel_launch(void* const* d_in, const int* in_sizes, int n_in,
                              void* d_out, int out_size, void* d_ws, size_t ws_size,
                              hipStream_t stream) {
  const int Bv = in_sizes[0] / (N_ * H_);   // 1024
  const int ns = out_size / Bv - 3;         // 120
  (void)hipFuncSetAttribute(reinterpret_cast<const void*>(gat_decoder),
                            hipFuncAttributeMaxDynamicSharedMemorySize, LDS_BYTES);
  gat_decoder<<<dim3(Bv), dim3(512), LDS_BYTES, stream>>>(
      (const float*)d_in[0],  (const float*)d_in[1],  (const float*)d_in[2],
      (const float*)d_in[3],  (const float*)d_in[4],  (const float*)d_in[5],
      (const float*)d_in[6],  (const float*)d_in[7],  (const float*)d_in[8],
      (const float*)d_in[9],  (const float*)d_in[10], (const float*)d_in[11],
      (const float*)d_in[12], (const float*)d_in[13], (const float*)d_in[14],
      (const int*)d_in[16],
      (float*)d_out, Bv, ns);
}